// Round 1
// 422.359 us; speedup vs baseline: 1.2353x; 1.2353x over previous
//
#include <hip/hip_runtime.h>

#define B_ 16
#define C_ 128
#define N_ 16384
#define TN 32

typedef __attribute__((ext_vector_type(8))) short short8;
typedef __attribute__((ext_vector_type(4))) float f32x4;

__device__ inline unsigned short bf16_rn(float x) {
  unsigned u = __float_as_uint(x);
  unsigned r = u + 0x7FFFu + ((u >> 16) & 1u);
  return (unsigned short)(r >> 16);
}

__device__ inline float u16hi_f(unsigned u) { return __uint_as_float(u & 0xFFFF0000u); }
__device__ inline float u16lo_f(unsigned u) { return __uint_as_float(u << 16); }

// Merged prep: Wk/Wv -> bf16 hi/lo split; block 0 additionally computes
// wqsum[i] = sum_o Wq[o][i].
__global__ __launch_bounds__(256) void prep_kernel(
    const float* __restrict__ Wq, const float* __restrict__ Wk, const float* __restrict__ Wv,
    float* __restrict__ wqsum,
    unsigned short* __restrict__ WkHi, unsigned short* __restrict__ WkLo,
    unsigned short* __restrict__ WvHi, unsigned short* __restrict__ WvLo) {
  int idx = blockIdx.x * 256 + threadIdx.x;  // 0..16383
  {
    float x = Wk[idx];
    unsigned short h = bf16_rn(x);
    WkHi[idx] = h;
    WkLo[idx] = bf16_rn(x - __uint_as_float(((unsigned)h) << 16));
  }
  {
    float x = Wv[idx];
    unsigned short h = bf16_rn(x);
    WvHi[idx] = h;
    WvLo[idx] = bf16_rn(x - __uint_as_float(((unsigned)h) << 16));
  }
  if (blockIdx.x == 0 && threadIdx.x < C_) {
    int i = threadIdx.x;
    float s = 0.f;
#pragma unroll 8
    for (int o = 0; o < C_; ++o) s += Wq[o * C_ + i];
    wqsum[i] = s;
  }
}

// Main: one block per (batch, 32-col tile). 4 waves, j-split: wave w owns output
// channels j in [32w, 32w+32) for ALL 32 columns. Weight fragments are
// register-cached per jt and reused across column tiles (weight global traffic
// /4 vs n-split). LDS = 34 KB -> 4 blocks/CU (16 waves/CU).
// Softmax over j crosses waves: online-softmax merge via 2 LDS reduction rounds.
// LDS X layout: [n][i] bf16, rows of 128, 8-elem chunks XOR-swizzled by
// f(n) = (n&15) ^ ((n>>2)&7).
__global__ __launch_bounds__(256, 4) void csa_mfma_kernel(
    const float* __restrict__ feature, const float* __restrict__ position,
    const float* __restrict__ wqsum,
    const unsigned short* __restrict__ WkHi, const unsigned short* __restrict__ WkLo,
    const unsigned short* __restrict__ WvHi, const unsigned short* __restrict__ WvLo,
    float* __restrict__ out) {
  __shared__ unsigned short posHi[TN * 128];
  __shared__ unsigned short posLo[TN * 128];
  __shared__ unsigned short featHi[TN * 128];
  __shared__ unsigned short featLo[TN * 128];
  __shared__ float red0[4][TN];  // sq partials (per wave i-slice)
  __shared__ float red1[4][TN];  // ksum partials (per wave j-slice)
  __shared__ float red2[4][TN];  // per-wave local max
  __shared__ float red3[4][TN];  // per-wave exp-sum

  const int tid = threadIdx.x;
  const int lane = tid & 63;
  const int w = tid >> 6;   // wave: owns j in [32w, 32w+32)
  const int m = lane & 15;  // column-within-16 / A-row
  const int q = lane >> 4;  // quad
  const int b = blockIdx.x >> 9;
  const int n0 = (blockIdx.x & 511) * TN;

  const float* pos_g = position + (size_t)b * C_ * N_ + n0;
  const float* feat_g = feature + (size_t)b * C_ * N_ + n0;

  // ---- stage + convert both tiles to hi/lo bf16 in LDS ----
  {
    const int g = tid >> 3;        // 0..31
    const int n4 = (tid & 7) * 4;  // col group
#pragma unroll
    for (int it = 0; it < 2; ++it) {
      int i = 64 * it + 2 * g;  // even row; handle rows i, i+1
      float4 p0 = *(const float4*)(pos_g + (size_t)i * N_ + n4);
      float4 p1 = *(const float4*)(pos_g + (size_t)(i + 1) * N_ + n4);
      float4 f0 = *(const float4*)(feat_g + (size_t)i * N_ + n4);
      float4 f1 = *(const float4*)(feat_g + (size_t)(i + 1) * N_ + n4);
      const float* P0 = (const float*)&p0;
      const float* P1 = (const float*)&p1;
      const float* F0 = (const float*)&f0;
      const float* F1 = (const float*)&f1;
      int c8 = (i >> 3) * 8;
      int ioff = i & 7;  // even
#pragma unroll
      for (int d = 0; d < 4; ++d) {
        int n = n4 + d;
        int fn8 = ((n & 15) ^ ((n >> 2) & 7)) * 8;
        int hw = n * 128 + (c8 ^ fn8) + ioff;
        {
          unsigned short h0 = bf16_rn(P0[d]), h1 = bf16_rn(P1[d]);
          float l0 = P0[d] - __uint_as_float(((unsigned)h0) << 16);
          float l1 = P1[d] - __uint_as_float(((unsigned)h1) << 16);
          *(unsigned*)(posHi + hw) = (unsigned)h0 | ((unsigned)h1 << 16);
          *(unsigned*)(posLo + hw) = (unsigned)bf16_rn(l0) | ((unsigned)bf16_rn(l1) << 16);
        }
        {
          unsigned short h0 = bf16_rn(F0[d]), h1 = bf16_rn(F1[d]);
          float l0 = F0[d] - __uint_as_float(((unsigned)h0) << 16);
          float l1 = F1[d] - __uint_as_float(((unsigned)h1) << 16);
          *(unsigned*)(featHi + hw) = (unsigned)h0 | ((unsigned)h1 << 16);
          *(unsigned*)(featLo + hw) = (unsigned)bf16_rn(l0) | ((unsigned)bf16_rn(l1) << 16);
        }
      }
    }
  }
  __syncthreads();

  // per-column-tile LDS row bases for this lane (col n = nt*16 + m)
  int rb[2], f8[2];
#pragma unroll
  for (int nt = 0; nt < 2; ++nt) {
    int n = nt * 16 + m;
    rb[nt] = n * 128;
    f8[nt] = ((n & 15) ^ ((n >> 2) & 7)) * 8;
  }

  // ---- k-GEMM: k[j][n], j = 32w + 16jt + 4q + r, n = nt*16 + m ----
  f32x4 acck[2][2];
#pragma unroll
  for (int jt = 0; jt < 2; ++jt)
#pragma unroll
    for (int nt = 0; nt < 2; ++nt) acck[jt][nt] = (f32x4){0.f, 0.f, 0.f, 0.f};

#pragma unroll
  for (int jt = 0; jt < 2; ++jt) {
    const int arow = (32 * w + 16 * jt + m) * 128 + q * 8;
    short8 ah[4], al[4];  // weight frags register-cached, reused over nt
#pragma unroll
    for (int kk = 0; kk < 4; ++kk) {
      ah[kk] = *(const short8*)(WkHi + arow + kk * 32);
      al[kk] = *(const short8*)(WkLo + arow + kk * 32);
    }
#pragma unroll
    for (int kk = 0; kk < 4; ++kk) {
      int co = (kk * 4 + q) * 8;
      short8 bh0 = *(const short8*)(posHi + rb[0] + (co ^ f8[0]));
      short8 bl0 = *(const short8*)(posLo + rb[0] + (co ^ f8[0]));
      short8 bh1 = *(const short8*)(posHi + rb[1] + (co ^ f8[1]));
      short8 bl1 = *(const short8*)(posLo + rb[1] + (co ^ f8[1]));
      acck[jt][0] = __builtin_amdgcn_mfma_f32_16x16x32_bf16(ah[kk], bh0, acck[jt][0], 0, 0, 0);
      acck[jt][1] = __builtin_amdgcn_mfma_f32_16x16x32_bf16(ah[kk], bh1, acck[jt][1], 0, 0, 0);
      acck[jt][0] = __builtin_amdgcn_mfma_f32_16x16x32_bf16(ah[kk], bl0, acck[jt][0], 0, 0, 0);
      acck[jt][1] = __builtin_amdgcn_mfma_f32_16x16x32_bf16(ah[kk], bl1, acck[jt][1], 0, 0, 0);
      acck[jt][0] = __builtin_amdgcn_mfma_f32_16x16x32_bf16(al[kk], bh0, acck[jt][0], 0, 0, 0);
      acck[jt][1] = __builtin_amdgcn_mfma_f32_16x16x32_bf16(al[kk], bh1, acck[jt][1], 0, 0, 0);
    }
  }

  // ---- v-GEMM ----
  f32x4 accv[2][2];
#pragma unroll
  for (int jt = 0; jt < 2; ++jt)
#pragma unroll
    for (int nt = 0; nt < 2; ++nt) accv[jt][nt] = (f32x4){0.f, 0.f, 0.f, 0.f};

#pragma unroll
  for (int jt = 0; jt < 2; ++jt) {
    const int arow = (32 * w + 16 * jt + m) * 128 + q * 8;
    short8 ah[4], al[4];
#pragma unroll
    for (int kk = 0; kk < 4; ++kk) {
      ah[kk] = *(const short8*)(WvHi + arow + kk * 32);
      al[kk] = *(const short8*)(WvLo + arow + kk * 32);
    }
#pragma unroll
    for (int kk = 0; kk < 4; ++kk) {
      int co = (kk * 4 + q) * 8;
      short8 bh0 = *(const short8*)(featHi + rb[0] + (co ^ f8[0]));
      short8 bl0 = *(const short8*)(featLo + rb[0] + (co ^ f8[0]));
      short8 bh1 = *(const short8*)(featHi + rb[1] + (co ^ f8[1]));
      short8 bl1 = *(const short8*)(featLo + rb[1] + (co ^ f8[1]));
      accv[jt][0] = __builtin_amdgcn_mfma_f32_16x16x32_bf16(ah[kk], bh0, accv[jt][0], 0, 0, 0);
      accv[jt][1] = __builtin_amdgcn_mfma_f32_16x16x32_bf16(ah[kk], bh1, accv[jt][1], 0, 0, 0);
      accv[jt][0] = __builtin_amdgcn_mfma_f32_16x16x32_bf16(ah[kk], bl0, accv[jt][0], 0, 0, 0);
      accv[jt][1] = __builtin_amdgcn_mfma_f32_16x16x32_bf16(ah[kk], bl1, accv[jt][1], 0, 0, 0);
      accv[jt][0] = __builtin_amdgcn_mfma_f32_16x16x32_bf16(al[kk], bh0, accv[jt][0], 0, 0, 0);
      accv[jt][1] = __builtin_amdgcn_mfma_f32_16x16x32_bf16(al[kk], bh1, accv[jt][1], 0, 0, 0);
    }
  }

  // ---- sq partial: wave w covers i in [32w, 32w+32); lane handles 8 i from i0 ----
  float sqp[2], kp[2];
  {
    const int i0 = 32 * w + 8 * q;  // 8-aligned: one full LDS chunk
    float4 wqa = *(const float4*)(wqsum + i0);
    float4 wqb = *(const float4*)(wqsum + i0 + 4);
    const int cbase = (i0 >> 3) * 8;
#pragma unroll
    for (int nt = 0; nt < 2; ++nt) {
      int hw = rb[nt] + (cbase ^ f8[nt]);
      unsigned h01 = *(const unsigned*)(posHi + hw);
      unsigned h23 = *(const unsigned*)(posHi + hw + 2);
      unsigned h45 = *(const unsigned*)(posHi + hw + 4);
      unsigned h67 = *(const unsigned*)(posHi + hw + 6);
      unsigned l01 = *(const unsigned*)(posLo + hw);
      unsigned l23 = *(const unsigned*)(posLo + hw + 2);
      unsigned l45 = *(const unsigned*)(posLo + hw + 4);
      unsigned l67 = *(const unsigned*)(posLo + hw + 6);
      float s = wqa.x * (u16lo_f(h01) + u16lo_f(l01));
      s = fmaf(wqa.y, u16hi_f(h01) + u16hi_f(l01), s);
      s = fmaf(wqa.z, u16lo_f(h23) + u16lo_f(l23), s);
      s = fmaf(wqa.w, u16hi_f(h23) + u16hi_f(l23), s);
      s = fmaf(wqb.x, u16lo_f(h45) + u16lo_f(l45), s);
      s = fmaf(wqb.y, u16hi_f(h45) + u16hi_f(l45), s);
      s = fmaf(wqb.z, u16lo_f(h67) + u16lo_f(l67), s);
      s = fmaf(wqb.w, u16hi_f(h67) + u16hi_f(l67), s);
      s += __shfl_xor(s, 16, 64);
      s += __shfl_xor(s, 32, 64);
      sqp[nt] = s;
    }
  }
  // ---- ksum partial over this wave's 32 j ----
#pragma unroll
  for (int nt = 0; nt < 2; ++nt) {
    float s = 0.f;
#pragma unroll
    for (int jt = 0; jt < 2; ++jt)
      s += acck[jt][nt][0] + acck[jt][nt][1] + acck[jt][nt][2] + acck[jt][nt][3];
    s += __shfl_xor(s, 16, 64);
    s += __shfl_xor(s, 32, 64);
    kp[nt] = s;
  }
  if (q == 0) {
#pragma unroll
    for (int nt = 0; nt < 2; ++nt) {
      red0[w][nt * 16 + m] = sqp[nt];
      red1[w][nt * 16 + m] = kp[nt];
    }
  }
  __syncthreads();

  // ---- cross-wave: gg, then wave-local softmax stats (online merge) ----
  float mw[2], sw[2], attscale[2];
#pragma unroll
  for (int nt = 0; nt < 2; ++nt) {
    int c = nt * 16 + m;
    float ss = red0[0][c] + red0[1][c] + red0[2][c] + red0[3][c];
    float ks = red1[0][c] + red1[1][c] + red1[2][c] + red1[3][c];
    float g = ss / (1e-9f + ss * ks);
    float mx = g * acck[0][nt][0];
#pragma unroll
    for (int jt = 0; jt < 2; ++jt)
#pragma unroll
      for (int r = 0; r < 4; ++r) mx = fmaxf(mx, g * acck[jt][nt][r]);
    mx = fmaxf(mx, __shfl_xor(mx, 16, 64));
    mx = fmaxf(mx, __shfl_xor(mx, 32, 64));
    float s = 0.f;
#pragma unroll
    for (int jt = 0; jt < 2; ++jt)
#pragma unroll
      for (int r = 0; r < 4; ++r) {
        float p = __expf(fmaf(g, acck[jt][nt][r], -mx));
        acck[jt][nt][r] = p;  // reuse as unnormalized attention
        s += p;
      }
    s += __shfl_xor(s, 16, 64);
    s += __shfl_xor(s, 32, 64);
    mw[nt] = mx;
    sw[nt] = s;
  }
  if (q == 0) {
#pragma unroll
    for (int nt = 0; nt < 2; ++nt) {
      red2[w][nt * 16 + m] = mw[nt];
      red3[w][nt * 16 + m] = sw[nt];
    }
  }
  __syncthreads();
#pragma unroll
  for (int nt = 0; nt < 2; ++nt) {
    int c = nt * 16 + m;
    float M = red2[0][c];
    M = fmaxf(M, red2[1][c]);
    M = fmaxf(M, red2[2][c]);
    M = fmaxf(M, red2[3][c]);
    float es = red3[0][c] * __expf(red2[0][c] - M);
    es += red3[1][c] * __expf(red2[1][c] - M);
    es += red3[2][c] * __expf(red2[2][c] - M);
    es += red3[3][c] * __expf(red2[3][c] - M);
    attscale[nt] = __expf(mw[nt] - M) / es;  // es >= 1 (max-owning wave)
  }

  // ---- epilogue: out = att*v + feat (feat from hi+lo, err ~2^-17) ----
  float* outp = out + (size_t)b * C_ * N_ + n0 + m;
#pragma unroll
  for (int jt = 0; jt < 2; ++jt) {
    const int jb = 32 * w + 16 * jt + 4 * q;
    const int cj = (jb >> 3) * 8;
    const int joff = jb & 7;  // 0 or 4: rows jb..jb+3 share one chunk
#pragma unroll
    for (int nt = 0; nt < 2; ++nt) {
      int hw = rb[nt] + (cj ^ f8[nt]) + joff;
      unsigned fh01 = *(const unsigned*)(featHi + hw);
      unsigned fl01 = *(const unsigned*)(featLo + hw);
      unsigned fh23 = *(const unsigned*)(featHi + hw + 2);
      unsigned fl23 = *(const unsigned*)(featLo + hw + 2);
      float fv0 = u16lo_f(fh01) + u16lo_f(fl01);
      float fv1 = u16hi_f(fh01) + u16hi_f(fl01);
      float fv2 = u16lo_f(fh23) + u16lo_f(fl23);
      float fv3 = u16hi_f(fh23) + u16hi_f(fl23);
      float as = attscale[nt];
      size_t base = (size_t)jb * N_ + nt * 16;
      outp[base] = fmaf(acck[jt][nt][0] * as, accv[jt][nt][0], fv0);
      outp[base + N_] = fmaf(acck[jt][nt][1] * as, accv[jt][nt][1], fv1);
      outp[base + (size_t)2 * N_] = fmaf(acck[jt][nt][2] * as, accv[jt][nt][2], fv2);
      outp[base + (size_t)3 * N_] = fmaf(acck[jt][nt][3] * as, accv[jt][nt][3], fv3);
    }
  }
}

extern "C" void kernel_launch(void* const* d_in, const int* in_sizes, int n_in,
                              void* d_out, int out_size, void* d_ws, size_t ws_size,
                              hipStream_t stream) {
  const float* feature = (const float*)d_in[0];
  const float* position = (const float*)d_in[1];
  const float* Wq = (const float*)d_in[2];
  const float* Wk = (const float*)d_in[3];
  const float* Wv = (const float*)d_in[4];
  float* out = (float*)d_out;

  char* ws = (char*)d_ws;
  float* wqsum = (float*)ws;                           // 512 B
  unsigned short* WkHi = (unsigned short*)(ws + 512);  // 32 KB each
  unsigned short* WkLo = (unsigned short*)(ws + 512 + 32768);
  unsigned short* WvHi = (unsigned short*)(ws + 512 + 65536);
  unsigned short* WvLo = (unsigned short*)(ws + 512 + 98304);

  prep_kernel<<<64, 256, 0, stream>>>(Wq, Wk, Wv, wqsum, WkHi, WkLo, WvHi, WvLo);
  csa_mfma_kernel<<<B_ * (N_ / TN), 256, 0, stream>>>(feature, position, wqsum,
                                                      WkHi, WkLo, WvHi, WvLo, out);
}

// Round 2
// 398.977 us; speedup vs baseline: 1.3077x; 1.0586x over previous
//
#include <hip/hip_runtime.h>

#define B_ 16
#define C_ 128
#define N_ 16384
#define TN 32

typedef __attribute__((ext_vector_type(8))) short short8;
typedef __attribute__((ext_vector_type(4))) float f32x4;

__device__ inline unsigned short bf16_rn(float x) {
  unsigned u = __float_as_uint(x);
  unsigned r = u + 0x7FFFu + ((u >> 16) & 1u);
  return (unsigned short)(r >> 16);
}

// Packed f32x2 -> bf16x2 (RNE), 1 VALU inst. No builtin on gfx950 -> inline asm.
__device__ inline unsigned cvt_pk_bf16(float a, float b) {
  unsigned r;
  asm("v_cvt_pk_bf16_f32 %0, %1, %2" : "=v"(r) : "v"(a), "v"(b));
  return r;
}

// Merged prep: Wk -> bf16 hi/lo split (k-path keeps split precision),
// Wv -> bf16 hi only (v-path is bf16: att*v tolerates ~2^-9),
// block 0 computes wqsum[i] = sum_o Wq[o][i].
__global__ __launch_bounds__(256) void prep_kernel(
    const float* __restrict__ Wq, const float* __restrict__ Wk, const float* __restrict__ Wv,
    float* __restrict__ wqsum,
    unsigned short* __restrict__ WkHi, unsigned short* __restrict__ WkLo,
    unsigned short* __restrict__ WvHi) {
  int idx = blockIdx.x * 256 + threadIdx.x;  // 0..16383
  {
    float x = Wk[idx];
    unsigned short h = bf16_rn(x);
    WkHi[idx] = h;
    WkLo[idx] = bf16_rn(x - __uint_as_float(((unsigned)h) << 16));
  }
  WvHi[idx] = bf16_rn(Wv[idx]);
  if (blockIdx.x == 0 && threadIdx.x < C_) {
    int i = threadIdx.x;
    float s = 0.f;
#pragma unroll 8
    for (int o = 0; o < C_; ++o) s += Wq[o * C_ + i];
    wqsum[i] = s;
  }
}

// Main: one block per (batch, 32-col tile). 4 waves, j-split: wave w owns output
// channels j in [32w, 32w+32) for ALL 32 columns.
// LDS = 26 KB (posHi/posLo/featHi + 2 KB reductions) -> 6 blocks/CU, 24 waves/CU.
// k-GEMM: split precision (3 mfma); v-GEMM: bf16 (1 mfma); epilogue feature from
// global f32 (exact, L2-hit). sq folded into staging (f32 fma + shuffle reduce).
// Softmax in exp2 domain. LDS X layout: [n][i] bf16, rows of 128, 8-elem chunks
// XOR-swizzled by f(n) = (n&15) ^ ((n>>2)&7).
__global__ __launch_bounds__(256, 6) void csa_mfma_kernel(
    const float* __restrict__ feature, const float* __restrict__ position,
    const float* __restrict__ wqsum,
    const unsigned short* __restrict__ WkHi, const unsigned short* __restrict__ WkLo,
    const unsigned short* __restrict__ WvHi,
    float* __restrict__ out) {
  __shared__ unsigned short posHi[TN * 128];
  __shared__ unsigned short posLo[TN * 128];
  __shared__ unsigned short featHi[TN * 128];
  __shared__ float red0[4][TN];  // sq wave-partials (written during staging)
  __shared__ float red1[4][TN];  // ksum wave-partials
  __shared__ float red2[4][TN];  // per-wave local max (log2 domain)
  __shared__ float red3[4][TN];  // per-wave exp2-sum

  const int tid = threadIdx.x;
  const int lane = tid & 63;
  const int w = tid >> 6;   // wave: owns j in [32w, 32w+32)
  const int m = lane & 15;  // column-within-16 / A-row
  const int q = lane >> 4;  // quad
  const int b = blockIdx.x >> 9;
  const int n0 = (blockIdx.x & 511) * TN;

  const float* pos_g = position + (size_t)b * C_ * N_ + n0;
  const float* feat_g = feature + (size_t)b * C_ * N_ + n0;

  // ---- stage + convert tiles; accumulate sq partials on f32 data ----
  {
    const int g = tid >> 3;        // 0..31 (wave w covers g in [8w,8w+8))
    const int n4 = (tid & 7) * 4;  // col group
    f32x4 sqa = (f32x4){0.f, 0.f, 0.f, 0.f};
#pragma unroll
    for (int it = 0; it < 2; ++it) {
      int i = 64 * it + 2 * g;  // even row; handle rows i, i+1
      float4 p0 = *(const float4*)(pos_g + (size_t)i * N_ + n4);
      float4 p1 = *(const float4*)(pos_g + (size_t)(i + 1) * N_ + n4);
      float4 f0 = *(const float4*)(feat_g + (size_t)i * N_ + n4);
      float4 f1 = *(const float4*)(feat_g + (size_t)(i + 1) * N_ + n4);
      float2 wq2 = *(const float2*)(wqsum + i);
      const float* P0 = (const float*)&p0;
      const float* P1 = (const float*)&p1;
      const float* F0 = (const float*)&f0;
      const float* F1 = (const float*)&f1;
      int c8 = (i >> 3) * 8;
      int ioff = i & 7;  // even
#pragma unroll
      for (int d = 0; d < 4; ++d) {
        int n = n4 + d;
        int fn8 = ((n & 15) ^ ((n >> 2) & 7)) * 8;
        int hw = n * 128 + (c8 ^ fn8) + ioff;
        float x0 = P0[d], x1 = P1[d];
        unsigned hu = cvt_pk_bf16(x0, x1);
        *(unsigned*)(posHi + hw) = hu;
        float l0 = x0 - __uint_as_float(hu << 16);
        float l1 = x1 - __uint_as_float(hu & 0xFFFF0000u);
        *(unsigned*)(posLo + hw) = cvt_pk_bf16(l0, l1);
        *(unsigned*)(featHi + hw) = cvt_pk_bf16(F0[d], F1[d]);
        sqa[d] = fmaf(wq2.x, x0, fmaf(wq2.y, x1, sqa[d]));
      }
    }
    // reduce sq partials over the 8 g-lanes sharing this column group
#pragma unroll
    for (int d = 0; d < 4; ++d) {
      float s = sqa[d];
      s += __shfl_xor(s, 8, 64);
      s += __shfl_xor(s, 16, 64);
      s += __shfl_xor(s, 32, 64);
      sqa[d] = s;
    }
    if (lane < 8) {
      *(float4*)&red0[w][lane * 4] =
          make_float4(sqa[0], sqa[1], sqa[2], sqa[3]);
    }
  }
  __syncthreads();

  // per-column-tile LDS row bases for this lane (col n = nt*16 + m)
  int rb[2], f8[2];
#pragma unroll
  for (int nt = 0; nt < 2; ++nt) {
    int n = nt * 16 + m;
    rb[nt] = n * 128;
    f8[nt] = ((n & 15) ^ ((n >> 2) & 7)) * 8;
  }

  // ---- k-GEMM (split precision): k[j][n], j = 32w + 16jt + 4q + r ----
  f32x4 acck[2][2];
#pragma unroll
  for (int jt = 0; jt < 2; ++jt)
#pragma unroll
    for (int nt = 0; nt < 2; ++nt) acck[jt][nt] = (f32x4){0.f, 0.f, 0.f, 0.f};

#pragma unroll
  for (int jt = 0; jt < 2; ++jt) {
    const int arow = (32 * w + 16 * jt + m) * 128 + q * 8;
    short8 ah[4], al[4];  // weight frags register-cached, reused over nt
#pragma unroll
    for (int kk = 0; kk < 4; ++kk) {
      ah[kk] = *(const short8*)(WkHi + arow + kk * 32);
      al[kk] = *(const short8*)(WkLo + arow + kk * 32);
    }
#pragma unroll
    for (int kk = 0; kk < 4; ++kk) {
      int co = (kk * 4 + q) * 8;
      short8 bh0 = *(const short8*)(posHi + rb[0] + (co ^ f8[0]));
      short8 bl0 = *(const short8*)(posLo + rb[0] + (co ^ f8[0]));
      short8 bh1 = *(const short8*)(posHi + rb[1] + (co ^ f8[1]));
      short8 bl1 = *(const short8*)(posLo + rb[1] + (co ^ f8[1]));
      acck[jt][0] = __builtin_amdgcn_mfma_f32_16x16x32_bf16(ah[kk], bh0, acck[jt][0], 0, 0, 0);
      acck[jt][1] = __builtin_amdgcn_mfma_f32_16x16x32_bf16(ah[kk], bh1, acck[jt][1], 0, 0, 0);
      acck[jt][0] = __builtin_amdgcn_mfma_f32_16x16x32_bf16(ah[kk], bl0, acck[jt][0], 0, 0, 0);
      acck[jt][1] = __builtin_amdgcn_mfma_f32_16x16x32_bf16(ah[kk], bl1, acck[jt][1], 0, 0, 0);
      acck[jt][0] = __builtin_amdgcn_mfma_f32_16x16x32_bf16(al[kk], bh0, acck[jt][0], 0, 0, 0);
      acck[jt][1] = __builtin_amdgcn_mfma_f32_16x16x32_bf16(al[kk], bh1, acck[jt][1], 0, 0, 0);
    }
  }

  // ---- ksum partial over this wave's 32 j; write round-1 ----
#pragma unroll
  for (int nt = 0; nt < 2; ++nt) {
    float s = 0.f;
#pragma unroll
    for (int jt = 0; jt < 2; ++jt)
      s += acck[jt][nt][0] + acck[jt][nt][1] + acck[jt][nt][2] + acck[jt][nt][3];
    s += __shfl_xor(s, 16, 64);
    s += __shfl_xor(s, 32, 64);
    if (q == 0) red1[w][nt * 16 + m] = s;
  }

  // ---- v-GEMM (bf16 only) — also hides the red1 write latency ----
  f32x4 accv[2][2];
#pragma unroll
  for (int jt = 0; jt < 2; ++jt)
#pragma unroll
    for (int nt = 0; nt < 2; ++nt) accv[jt][nt] = (f32x4){0.f, 0.f, 0.f, 0.f};

#pragma unroll
  for (int jt = 0; jt < 2; ++jt) {
    const int arow = (32 * w + 16 * jt + m) * 128 + q * 8;
    short8 ah[4];
#pragma unroll
    for (int kk = 0; kk < 4; ++kk) ah[kk] = *(const short8*)(WvHi + arow + kk * 32);
#pragma unroll
    for (int kk = 0; kk < 4; ++kk) {
      int co = (kk * 4 + q) * 8;
      short8 bh0 = *(const short8*)(featHi + rb[0] + (co ^ f8[0]));
      short8 bh1 = *(const short8*)(featHi + rb[1] + (co ^ f8[1]));
      accv[jt][0] = __builtin_amdgcn_mfma_f32_16x16x32_bf16(ah[kk], bh0, accv[jt][0], 0, 0, 0);
      accv[jt][1] = __builtin_amdgcn_mfma_f32_16x16x32_bf16(ah[kk], bh1, accv[jt][1], 0, 0, 0);
    }
  }
  __syncthreads();

  // ---- cross-wave: g, then wave-local softmax stats (exp2 domain) ----
  float mw[2], sw[2], attscale[2];
#pragma unroll
  for (int nt = 0; nt < 2; ++nt) {
    int c = nt * 16 + m;
    float ss = red0[0][c] + red0[1][c] + red0[2][c] + red0[3][c];
    float ks = red1[0][c] + red1[1][c] + red1[2][c] + red1[3][c];
    float gl = (ss / (1e-9f + ss * ks)) * 1.44269504f;  // fold log2(e)
    float mx = gl * acck[0][nt][0];
#pragma unroll
    for (int jt = 0; jt < 2; ++jt)
#pragma unroll
      for (int r = 0; r < 4; ++r) {
        float e = gl * acck[jt][nt][r];
        acck[jt][nt][r] = e;  // log2-domain energy
        mx = fmaxf(mx, e);
      }
    mx = fmaxf(mx, __shfl_xor(mx, 16, 64));
    mx = fmaxf(mx, __shfl_xor(mx, 32, 64));
    float s = 0.f;
#pragma unroll
    for (int jt = 0; jt < 2; ++jt)
#pragma unroll
      for (int r = 0; r < 4; ++r) {
        float p = exp2f(acck[jt][nt][r] - mx);
        acck[jt][nt][r] = p;  // unnormalized attention
        s += p;
      }
    s += __shfl_xor(s, 16, 64);
    s += __shfl_xor(s, 32, 64);
    mw[nt] = mx;
    sw[nt] = s;
  }
  if (q == 0) {
#pragma unroll
    for (int nt = 0; nt < 2; ++nt) {
      red2[w][nt * 16 + m] = mw[nt];
      red3[w][nt * 16 + m] = sw[nt];
    }
  }
  __syncthreads();
#pragma unroll
  for (int nt = 0; nt < 2; ++nt) {
    int c = nt * 16 + m;
    float M = red2[0][c];
    M = fmaxf(M, red2[1][c]);
    M = fmaxf(M, red2[2][c]);
    M = fmaxf(M, red2[3][c]);
    float es = red3[0][c] * exp2f(red2[0][c] - M);
    es += red3[1][c] * exp2f(red2[1][c] - M);
    es += red3[2][c] * exp2f(red2[2][c] - M);
    es += red3[3][c] * exp2f(red2[3][c] - M);
    attscale[nt] = exp2f(mw[nt] - M) / es;  // es >= 1 (max-owning wave)
  }

  // ---- epilogue: out = att*v + feature (feature exact from global f32) ----
  float* outp = out + (size_t)b * C_ * N_ + n0 + m;
  const float* finp = feature + (size_t)b * C_ * N_ + n0 + m;
#pragma unroll
  for (int jt = 0; jt < 2; ++jt) {
    const int jb = 32 * w + 16 * jt + 4 * q;
#pragma unroll
    for (int nt = 0; nt < 2; ++nt) {
      float as = attscale[nt];
      size_t base = (size_t)jb * N_ + nt * 16;
      float fv0 = finp[base];
      float fv1 = finp[base + N_];
      float fv2 = finp[base + (size_t)2 * N_];
      float fv3 = finp[base + (size_t)3 * N_];
      outp[base] = fmaf(acck[jt][nt][0] * as, accv[jt][nt][0], fv0);
      outp[base + N_] = fmaf(acck[jt][nt][1] * as, accv[jt][nt][1], fv1);
      outp[base + (size_t)2 * N_] = fmaf(acck[jt][nt][2] * as, accv[jt][nt][2], fv2);
      outp[base + (size_t)3 * N_] = fmaf(acck[jt][nt][3] * as, accv[jt][nt][3], fv3);
    }
  }
}

extern "C" void kernel_launch(void* const* d_in, const int* in_sizes, int n_in,
                              void* d_out, int out_size, void* d_ws, size_t ws_size,
                              hipStream_t stream) {
  const float* feature = (const float*)d_in[0];
  const float* position = (const float*)d_in[1];
  const float* Wq = (const float*)d_in[2];
  const float* Wk = (const float*)d_in[3];
  const float* Wv = (const float*)d_in[4];
  float* out = (float*)d_out;

  char* ws = (char*)d_ws;
  float* wqsum = (float*)ws;                           // 512 B
  unsigned short* WkHi = (unsigned short*)(ws + 512);  // 32 KB each
  unsigned short* WkLo = (unsigned short*)(ws + 512 + 32768);
  unsigned short* WvHi = (unsigned short*)(ws + 512 + 65536);

  prep_kernel<<<64, 256, 0, stream>>>(Wq, Wk, Wv, wqsum, WkHi, WkLo, WvHi);
  csa_mfma_kernel<<<B_ * (N_ / TN), 256, 0, stream>>>(feature, position, wqsum,
                                                      WkHi, WkLo, WvHi, out);
}